// Round 2
// baseline (15050.462 us; speedup 1.0000x reference)
//
#include <hip/hip_runtime.h>
#include <math.h>

// T=64, B=128, H=256, C=256, K=8, L=3, rows = B*K = 1024.
// Workspace layout (float units):
static constexpr size_t O_EMBW   = 0;         // [256 cls][1024 (u*4+g)] emb@Wih0^T + b0
static constexpr size_t O_WPT    = 262144;    // [256 k][256 c]
static constexpr size_t O_WIHT   = 327680;    // [3][256 k][1024 (u*4+g)]
static constexpr size_t O_WHHT   = 1114112;   // [3][256 k][1024]
static constexpr size_t O_BIASC  = 1900544;   // [2][256 u][4 g]
static constexpr size_t O_STATE  = 1902592;   // [1024][256]
static constexpr size_t O_PREFIX = 2164736;   // [1024]
static constexpr size_t O_H      = 2165760;   // [2 buf][3 l][1024][256]
static constexpr size_t O_C      = 3738624;
static constexpr size_t O_PREV   = 5311488;   // u8 [64][1024]  (16384 floats)
static constexpr size_t O_CLS    = 5327872;   // u8 [64][1024]
static constexpr size_t O_SLOT   = 5344256;   // uint[16 grp][16 member] barrier slots

__device__ __forceinline__ float sigf(float x){ return 1.0f/(1.0f + expf(-x)); }

// ---------------- one-time prep (coalesced reads, scattered writes) ----------
__global__ __launch_bounds__(256) void k_prep(
    const float* __restrict__ Wih, const float* __restrict__ Whh,
    const float* __restrict__ Wp,  const float* __restrict__ bih,
    const float* __restrict__ bhh,
    float* __restrict__ wihT, float* __restrict__ whhT,
    float* __restrict__ WpT, float* __restrict__ biasC)
{
  const int NT = 786432;
  const int TOTAL = 2*NT + 65536 + 2048;
  int stride = gridDim.x * blockDim.x;
  for (int i = blockIdx.x*blockDim.x + threadIdx.x; i < TOTAL; i += stride){
    if (i < NT){
      int l = i / 262144, r = i % 262144;      // r = row*256 + k
      int row = r >> 8, k = r & 255;
      int g = row >> 8, u = row & 255;
      wihT[(size_t)l*262144 + (k<<10) + (u<<2) + g] = Wih[i];
    } else if (i < 2*NT){
      int j = i - NT;
      int l = j / 262144, r = j % 262144;
      int row = r >> 8, k = r & 255;
      int g = row >> 8, u = row & 255;
      whhT[(size_t)l*262144 + (k<<10) + (u<<2) + g] = Whh[j];
    } else if (i < 2*NT + 65536){
      int j = i - 2*NT; int c = j >> 8, k = j & 255;
      WpT[(k<<8) + c] = Wp[j];
    } else {
      int j = i - 2*NT - 65536;
      int l = 1 + (j >> 10); int cg = j & 1023, u = cg >> 2, g = cg & 3;
      biasC[j] = bih[l*1024 + g*256 + u] + bhh[l*1024 + g*256 + u];
    }
  }
}

// ---------------- one-time: embW[cls][u*4+g] = emb@Wih0^T + bih0 + bhh0 ------
__global__ __launch_bounds__(256) void k_embW(
    const float* __restrict__ emb, const float* __restrict__ wih0T,
    const float* __restrict__ bih, const float* __restrict__ bhh,
    float* __restrict__ embW)
{
  const int cls = blockIdx.x, u = threadIdx.x;
  const float* er = emb + cls*256;
  float a0=0.f,a1=0.f,a2=0.f,a3=0.f;
  for (int k=0;k<256;k++){
    float ev = er[k];
    float4 w = *(const float4*)&wih0T[k*1024 + u*4];
    a0 = fmaf(ev, w.x, a0); a1 = fmaf(ev, w.y, a1);
    a2 = fmaf(ev, w.z, a2); a3 = fmaf(ev, w.w, a3);
  }
  a0 += bih[u]       + bhh[u];
  a1 += bih[256+u]   + bhh[256+u];
  a2 += bih[512+u]   + bhh[512+u];
  a3 += bih[768+u]   + bhh[768+u];
  *(float4*)&embW[cls*1024 + u*4] = make_float4(a0,a1,a2,a3);
}

// ---------------- init: state = x[0] broadcast, prefix init ------------------
__global__ __launch_bounds__(256) void k_init0(const float* __restrict__ x,
    float* __restrict__ state, float* __restrict__ prefix)
{
  int b = blockIdx.x, tid = threadIdx.x;
  float v = x[b*256 + tid];
  for (int k=0;k<8;k++) state[(size_t)(b*8+k)*256 + tid] = v;
  if (tid < 8) prefix[b*8+tid] = (tid==0) ? 0.0f : -1e30f;
}

// ---------------- init: one LSTM layer from zero state -----------------------
__global__ __launch_bounds__(256) void k_initL(const float* __restrict__ in, int inMul,
    const float* __restrict__ wT, const float* __restrict__ bihl, const float* __restrict__ bhhl,
    float* __restrict__ Hout, float* __restrict__ Cout)
{
  int b = blockIdx.x, u = threadIdx.x;
  const float* ir = in + (size_t)b*inMul;
  float a0=0.f,a1=0.f,a2=0.f,a3=0.f;
  for (int k=0;k<256;k++){
    float xv = ir[k];
    float4 w = *(const float4*)&wT[k*1024 + u*4];
    a0=fmaf(xv,w.x,a0); a1=fmaf(xv,w.y,a1); a2=fmaf(xv,w.z,a2); a3=fmaf(xv,w.w,a3);
  }
  float gi = a0 + bihl[u]     + bhhl[u];
  float gg = a2 + bihl[512+u] + bhhl[512+u];
  float go = a3 + bihl[768+u] + bhhl[768+u];
  float cn = sigf(gi)*tanhf(gg);
  float hn = sigf(go)*tanhf(cn);
  for (int k=0;k<8;k++){
    Hout[(size_t)(b*8+k)*256+u]=hn;
    Cout[(size_t)(b*8+k)*256+u]=cn;
  }
}

// ---------------- proj + log_softmax + top-8 for one sample ------------------
__device__ __forceinline__ void proj_phase(float* sm, int b,
    const float* __restrict__ WpT, const float* __restrict__ bp,
    const float* __restrict__ state, float* __restrict__ prefix,
    unsigned char* __restrict__ prevT, unsigned char* __restrict__ clsT)
{
  const int tid = threadIdx.x, c = tid;
  float* jnt  = sm;
  float* bwv  = sm + 2048; int* bwi  = (int*)(sm + 2052);
  float* sVal = sm + 2056; int* sPrev = (int*)(sm + 2064); int* sCls = (int*)(sm + 2072);

  const float* srow = state + (size_t)b*2048;
  float acc[8];
  #pragma unroll
  for (int i=0;i<8;i++) acc[i]=0.f;
  for (int k=0;k<256;k+=4){
    float w0 = WpT[(k+0)*256 + c];
    float w1 = WpT[(k+1)*256 + c];
    float w2 = WpT[(k+2)*256 + c];
    float w3 = WpT[(k+3)*256 + c];
    #pragma unroll
    for (int kb=0;kb<8;kb++){
      float4 sv = *(const float4*)&srow[kb*256 + k];
      acc[kb]=fmaf(sv.x,w0,acc[kb]); acc[kb]=fmaf(sv.y,w1,acc[kb]);
      acc[kb]=fmaf(sv.z,w2,acc[kb]); acc[kb]=fmaf(sv.w,w3,acc[kb]);
    }
  }
  float bpc = bp[c];
  #pragma unroll
  for (int kb=0;kb<8;kb++) jnt[kb*256+c] = acc[kb]+bpc;
  __syncthreads();

  const int w = tid>>6, lane = tid&63;
  for (int rep=0;rep<2;rep++){
    int kb = w + rep*4;
    float4 v = *(const float4*)&jnt[kb*256 + lane*4];
    float m = fmaxf(fmaxf(v.x,v.y),fmaxf(v.z,v.w));
    for (int off=32;off;off>>=1) m = fmaxf(m, __shfl_down(m,off));
    m = __shfl(m, 0);
    double s = exp((double)v.x-(double)m)+exp((double)v.y-(double)m)
             + exp((double)v.z-(double)m)+exp((double)v.w-(double)m);
    for (int off=32;off;off>>=1) s += __shfl_down(s,off);
    s = __shfl(s, 0);
    double lse = log(s);
    float pf = prefix[b*8+kb];
    float4 o;
    o.x = (float)((double)v.x - (double)m - lse) + pf;
    o.y = (float)((double)v.y - (double)m - lse) + pf;
    o.z = (float)((double)v.z - (double)m - lse) + pf;
    o.w = (float)((double)v.w - (double)m - lse) + pf;
    *(float4*)&jnt[kb*256+lane*4] = o;
  }
  __syncthreads();

  for (int r=0;r<8;r++){
    float bv = -INFINITY; int bi = 0;
    #pragma unroll
    for (int i=0;i<8;i++){
      int idx = tid*8+i; float v = jnt[idx];
      if (v > bv){ bv=v; bi=idx; }
    }
    for (int off=32;off;off>>=1){
      float ov = __shfl_down(bv,off); int oi = __shfl_down(bi,off);
      if (ov>bv || (ov==bv && oi<bi)){ bv=ov; bi=oi; }
    }
    if (lane==0){ bwv[w]=bv; bwi[w]=bi; }
    __syncthreads();
    if (tid==0){
      float BV=bwv[0]; int BI=bwi[0];
      for (int j=1;j<4;j++) if (bwv[j]>BV || (bwv[j]==BV && bwi[j]<BI)){BV=bwv[j];BI=bwi[j];}
      sVal[r]=BV; sPrev[r]=BI>>8; sCls[r]=BI&255;
      jnt[BI] = -INFINITY;
    }
    __syncthreads();
  }
  if (tid<8){
    prefix[b*8+tid]=sVal[tid];
    prevT[b*8+tid]=(unsigned char)sPrev[tid];
    clsT[b*8+tid]=(unsigned char)sCls[tid];
  }
}

// --------- gates GEMM + fused LSTM-cell epilogue for one 64x16u tile ---------
__device__ __attribute__((noinline)) void lstm_phase(
    float* As, float* Bs, int rb, int ub,
    const float* __restrict__ A1, const float* __restrict__ Hold,
    const float* __restrict__ Cold,
    const float* __restrict__ WT1, const float* __restrict__ WT2,
    const float* __restrict__ embW, const float* __restrict__ biasC,
    const unsigned char* __restrict__ prev, const unsigned char* __restrict__ cls,
    float* __restrict__ Hnew, float* __restrict__ Cnew,
    float* __restrict__ state, const float* __restrict__ xT, int KTOT)
{
  const int tid = threadIdx.x;
  const int rq = tid & 15, kq = tid >> 4;
  const int r0s = rq*4, k0s = kq*4;
  const int kk2 = tid >> 2, cq = (tid & 3) << 4;
  const int w = tid >> 6, lane = tid & 63;
  const int r0 = (lane >> 3) * 8, c0 = (lane & 7) * 8;

  int grow[4];
  #pragma unroll
  for (int i=0;i<4;i++){
    int rg = rb + r0s + i;
    grow[i] = (rg & ~7) + (int)prev[rg];
  }

  float acc[64];
  #pragma unroll
  for (int i=0;i<64;i++) acc[i]=0.f;

  const int nch = KTOT >> 6;
  float4 va0,va1,va2,va3, vb0,vb1,vb2,vb3;

  auto loadAB = [&](int kb){
    const bool haveA1 = (A1 != nullptr);
    const bool dense = haveA1 && (kb < 256);
    if (dense){
      const float* p = A1 + (size_t)(rb + r0s)*256 + kb + k0s;
      va0 = *(const float4*)(p);
      va1 = *(const float4*)(p + 256);
      va2 = *(const float4*)(p + 512);
      va3 = *(const float4*)(p + 768);
    } else {
      const int ko = kb - (haveA1 ? 256 : 0);
      va0 = *(const float4*)&Hold[(size_t)grow[0]*256 + ko + k0s];
      va1 = *(const float4*)&Hold[(size_t)grow[1]*256 + ko + k0s];
      va2 = *(const float4*)&Hold[(size_t)grow[2]*256 + ko + k0s];
      va3 = *(const float4*)&Hold[(size_t)grow[3]*256 + ko + k0s];
    }
    const float* WT; int kr;
    if (dense){ WT = WT1; kr = kb; }
    else { WT = WT2; kr = kb - (haveA1 ? 256 : 0); }
    const float* q = WT + (size_t)(kr + kk2)*1024 + ub*4 + cq;
    vb0 = *(const float4*)(q);
    vb1 = *(const float4*)(q+4);
    vb2 = *(const float4*)(q+8);
    vb3 = *(const float4*)(q+12);
  };
  auto storeAB = [&](){
    *(float4*)&As[(k0s+0)*68 + r0s] = make_float4(va0.x,va1.x,va2.x,va3.x);
    *(float4*)&As[(k0s+1)*68 + r0s] = make_float4(va0.y,va1.y,va2.y,va3.y);
    *(float4*)&As[(k0s+2)*68 + r0s] = make_float4(va0.z,va1.z,va2.z,va3.z);
    *(float4*)&As[(k0s+3)*68 + r0s] = make_float4(va0.w,va1.w,va2.w,va3.w);
    *(float4*)&Bs[kk2*68 + cq + 0]  = vb0;
    *(float4*)&Bs[kk2*68 + cq + 4]  = vb1;
    *(float4*)&Bs[kk2*68 + cq + 8]  = vb2;
    *(float4*)&Bs[kk2*68 + cq + 12] = vb3;
  };

  loadAB(0);
  for (int ch=0; ch<nch; ++ch){
    if (ch) __syncthreads();
    storeAB();
    __syncthreads();
    if (ch+1 < nch) loadAB((ch+1)<<6);
    const int kkb = w<<4;
    #pragma unroll
    for (int q2=0;q2<16;q2++){
      const int kk = kkb + q2;
      float a[8], bbv[8];
      *(float4*)&a[0]   = *(const float4*)&As[kk*68 + r0];
      *(float4*)&a[4]   = *(const float4*)&As[kk*68 + r0 + 4];
      *(float4*)&bbv[0] = *(const float4*)&Bs[kk*68 + c0];
      *(float4*)&bbv[4] = *(const float4*)&Bs[kk*68 + c0 + 4];
      #pragma unroll
      for (int i=0;i<8;i++)
        #pragma unroll
        for (int j=0;j<8;j++)
          acc[i*8+j] = fmaf(a[i], bbv[j], acc[i*8+j]);
    }
  }
  __syncthreads();

  #define ROFF(r,cl) ((r)*68 + ((((cl)>>3) ^ ((r)&7))<<3) + ((cl)&7))
  if (w==0 || w==2){
    float* red = (w==0) ? As : Bs;
    #pragma unroll
    for (int i=0;i<8;i++){
      *(float4*)&red[ROFF(r0+i, c0)]   = make_float4(acc[i*8+0],acc[i*8+1],acc[i*8+2],acc[i*8+3]);
      *(float4*)&red[ROFF(r0+i, c0+4)] = make_float4(acc[i*8+4],acc[i*8+5],acc[i*8+6],acc[i*8+7]);
    }
  }
  __syncthreads();
  if (w==1 || w==3){
    float* red = (w==1) ? As : Bs;
    #pragma unroll
    for (int i=0;i<8;i++){
      float4 p0 = *(float4*)&red[ROFF(r0+i, c0)];
      float4 p1 = *(float4*)&red[ROFF(r0+i, c0+4)];
      p0.x+=acc[i*8+0]; p0.y+=acc[i*8+1]; p0.z+=acc[i*8+2]; p0.w+=acc[i*8+3];
      p1.x+=acc[i*8+4]; p1.y+=acc[i*8+5]; p1.z+=acc[i*8+6]; p1.w+=acc[i*8+7];
      *(float4*)&red[ROFF(r0+i, c0)]   = p0;
      *(float4*)&red[ROFF(r0+i, c0+4)] = p1;
    }
  }
  __syncthreads();

  {
    const int row = tid >> 2, tq = tid & 3;
    const int rowg = rb + row;
    const int gr = (rowg & ~7) + (int)prev[rowg];
    const int u0 = tq*4;
    float4 co = *(const float4*)&Cold[(size_t)gr*256 + ub + u0];
    float cov[4] = {co.x,co.y,co.z,co.w};
    float hnv[4], cnv[4];
    const float* basep = (embW != nullptr)
        ? (embW + (size_t)cls[rowg]*1024 + (ub+u0)*4)
        : (biasC + (ub+u0)*4);
    #pragma unroll
    for (int q2=0;q2<4;q2++){
      int colL = (u0+q2)*4;
      float4 g0 = *(const float4*)&As[ROFF(row,colL)];
      float4 g1 = *(const float4*)&Bs[ROFF(row,colL)];
      float4 bs = *(const float4*)&basep[q2*4];
      float gi = g0.x+g1.x+bs.x;
      float gf = g0.y+g1.y+bs.y;
      float gg = g0.z+g1.z+bs.z;
      float go = g0.w+g1.w+bs.w;
      float cn = sigf(gf)*cov[q2] + sigf(gi)*tanhf(gg);
      float hn = sigf(go)*tanhf(cn);
      cnv[q2]=cn; hnv[q2]=hn;
    }
    size_t ob = (size_t)rowg*256 + ub + u0;
    *(float4*)&Hnew[ob] = make_float4(hnv[0],hnv[1],hnv[2],hnv[3]);
    *(float4*)&Cnew[ob] = make_float4(cnv[0],cnv[1],cnv[2],cnv[3]);
    if (state){
      const float4 xv = *(const float4*)&xT[(size_t)(rowg>>3)*256 + ub + u0];
      *(float4*)&state[ob] = make_float4(hnv[0]+xv.x, hnv[1]+xv.y, hnv[2]+xv.z, hnv[3]+xv.w);
    }
  }
  #undef ROFF
}

// ---------------- group barrier: 16 blocks, device-scope ---------------------
__device__ __forceinline__ void group_barrier(unsigned* gs, int member, unsigned ph){
  __syncthreads();                       // drains each wave's stores (vmcnt 0)
  if (threadIdx.x == 0){
    __threadfence();                     // agent-scope release (L2 writeback)
    __hip_atomic_store(&gs[member], ph, __ATOMIC_RELAXED, __HIP_MEMORY_SCOPE_AGENT);
  }
  if (threadIdx.x < 16){
    while (__hip_atomic_load(&gs[threadIdx.x], __ATOMIC_RELAXED, __HIP_MEMORY_SCOPE_AGENT) < ph) {}
  }
  __syncthreads();
  __threadfence();                       // agent-scope acquire (L1 invalidate)
}

// ---------------- persistent: all 64 steps -----------------------------------
__global__ __launch_bounds__(256) void k_steps(
    const float* __restrict__ x, const float* __restrict__ bp,
    float* __restrict__ ws, unsigned* __restrict__ slots)
{
  __shared__ float smem[8704];
  float* As = smem; float* Bs = smem + 4352;
  const int bx = blockIdx.x;
  const int g = bx & 15, m = bx >> 4;      // member blocks of group g share an XCD
  const int rb = g << 6, ub = m << 4;

  float* embW  = ws + O_EMBW;
  float* WpT   = ws + O_WPT;
  float* wihT  = ws + O_WIHT;
  float* whhT  = ws + O_WHHT;
  float* biasC = ws + O_BIASC;
  float* state = ws + O_STATE;
  float* prefix= ws + O_PREFIX;
  unsigned char* prevU = (unsigned char*)(ws + O_PREV);
  unsigned char* clsU  = (unsigned char*)(ws + O_CLS);
  unsigned* gs = slots + g*16;

  auto Hb = [&](int buf,int l){ return ws + O_H + (size_t)(buf*3+l)*262144; };
  auto Cb = [&](int buf,int l){ return ws + O_C + (size_t)(buf*3+l)*262144; };

  unsigned ph = 0;
  for (int t=0;t<64;t++){
    const int cb = t&1, nb = cb^1;
    unsigned char* pv = prevU + (t<<10);
    unsigned char* cl = clsU  + (t<<10);

    if (m < 8) proj_phase(smem, (g<<3)+m, WpT, bp, state, prefix, pv, cl);
    group_barrier(gs, m, ++ph);

    lstm_phase(As,Bs, rb, ub, nullptr, Hb(cb,0), Cb(cb,0), nullptr, whhT,
               embW, nullptr, pv, cl, Hb(nb,0), Cb(nb,0), nullptr, nullptr, 256);
    group_barrier(gs, m, ++ph);

    lstm_phase(As,Bs, rb, ub, Hb(nb,0), Hb(cb,1), Cb(cb,1), wihT+262144, whhT+262144,
               nullptr, biasC, pv, cl, Hb(nb,1), Cb(nb,1), nullptr, nullptr, 512);
    group_barrier(gs, m, ++ph);

    const int tn = (t+1 < 64) ? (t+1) : 63;
    lstm_phase(As,Bs, rb, ub, Hb(nb,1), Hb(cb,2), Cb(cb,2), wihT+524288, whhT+524288,
               nullptr, biasC+1024, pv, cl, Hb(nb,2), Cb(nb,2),
               state, x + (size_t)tn*32768, 512);
    group_barrier(gs, m, ++ph);
  }
}

// ---------------- fallback wrappers (multi-dispatch path) --------------------
__global__ __launch_bounds__(256) void k_proj(
    const float* __restrict__ WpT, const float* __restrict__ bp,
    const float* __restrict__ state, float* __restrict__ prefix,
    unsigned char* __restrict__ prevT, unsigned char* __restrict__ clsT)
{
  __shared__ float sm[2080];
  proj_phase(sm, blockIdx.x, WpT, bp, state, prefix, prevT, clsT);
}

__global__ __launch_bounds__(256) void k_lstm(
    const float* A1, const float* Hold, const float* Cold,
    const float* WT1, const float* WT2,
    const float* embW, const float* biasC,
    const unsigned char* prev, const unsigned char* cls,
    float* Hnew, float* Cnew, float* state, const float* xT, int KTOT)
{
  __shared__ float smem[8704];
  lstm_phase(smem, smem+4352, (blockIdx.x & 15) << 6, (blockIdx.x >> 4) << 4,
             A1, Hold, Cold, WT1, WT2, embW, biasC, prev, cls,
             Hnew, Cnew, state, xT, KTOT);
}

// ---------------- final: backtrace choices + copy prefix ---------------------
__global__ __launch_bounds__(256) void k_out(const unsigned char* __restrict__ prevU,
    const unsigned char* __restrict__ clsU, const float* __restrict__ prefix,
    float* __restrict__ out)
{
  int t0 = blockIdx.x*blockDim.x + threadIdx.x;  // (b*8+k)
  if (t0 >= 1024) return;
  int b = t0 >> 3, k = t0 & 7;
  int e = k;
  for (int t=63;t>=0;--t){
    int base = t*1024 + b*8;
    out[(size_t)t0*64 + t] = (float)clsU[base + e];
    e = (int)prevU[base + e];
  }
  out[65536 + t0] = prefix[t0];
}

extern "C" void kernel_launch(void* const* d_in, const int* in_sizes, int n_in,
                              void* d_out, int out_size, void* d_ws, size_t ws_size,
                              hipStream_t stream)
{
  const float* x   = (const float*)d_in[0];
  const float* emb = (const float*)d_in[1];
  const float* Wih = (const float*)d_in[2];
  const float* Whh = (const float*)d_in[3];
  const float* bih = (const float*)d_in[4];
  const float* bhh = (const float*)d_in[5];
  const float* Wp  = (const float*)d_in[6];
  const float* bp  = (const float*)d_in[7];
  float* ws = (float*)d_ws;

  float* embW   = ws + O_EMBW;
  float* WpT    = ws + O_WPT;
  float* wihT   = ws + O_WIHT;
  float* whhT   = ws + O_WHHT;
  float* biasC  = ws + O_BIASC;
  float* state  = ws + O_STATE;
  float* prefix = ws + O_PREFIX;
  unsigned char* prevU = (unsigned char*)(ws + O_PREV);
  unsigned char* clsU  = (unsigned char*)(ws + O_CLS);
  unsigned* slots = (unsigned*)(ws + O_SLOT);

  auto Hb = [&](int buf, int l){ return ws + O_H + (size_t)(buf*3+l)*262144; };
  auto Cb = [&](int buf, int l){ return ws + O_C + (size_t)(buf*3+l)*262144; };

  k_prep<<<256,256,0,stream>>>(Wih,Whh,Wp,bih,bhh,wihT,whhT,WpT,biasC);
  k_embW<<<256,256,0,stream>>>(emb, wihT, bih, bhh, embW);
  k_init0<<<128,256,0,stream>>>(x, state, prefix);
  k_initL<<<128,256,0,stream>>>(x,        256,  wihT,          bih,      bhh,      Hb(0,0), Cb(0,0));
  k_initL<<<128,256,0,stream>>>(Hb(0,0),  2048, wihT+262144,   bih+1024, bhh+1024, Hb(0,1), Cb(0,1));
  k_initL<<<128,256,0,stream>>>(Hb(0,1),  2048, wihT+524288,   bih+2048, bhh+2048, Hb(0,2), Cb(0,2));

  hipMemsetAsync(slots, 0, 1024, stream);

  const float* xp = x; const float* bpp = bp; float* wsp = ws; unsigned* slp = slots;
  void* kargs[] = { (void*)&xp, (void*)&bpp, (void*)&wsp, (void*)&slp };
  hipError_t ce = hipLaunchCooperativeKernel(
      reinterpret_cast<const void*>(&k_steps), dim3(256), dim3(256), kargs, 0, stream);

  if (ce != hipSuccess){
    // fallback: multi-dispatch path (identical math)
    (void)hipGetLastError();
    for (int t=0;t<64;t++){
      int cbuf = t&1, nbuf = cbuf^1;
      unsigned char* pv = prevU + t*1024;
      unsigned char* cl = clsU  + t*1024;
      k_proj<<<128,256,0,stream>>>(WpT, bp, state, prefix, pv, cl);
      k_lstm<<<256,256,0,stream>>>(nullptr, Hb(cbuf,0), Cb(cbuf,0), nullptr, whhT, embW, nullptr,
                                   pv, cl, Hb(nbuf,0), Cb(nbuf,0), nullptr, nullptr, 256);
      k_lstm<<<256,256,0,stream>>>(Hb(nbuf,0), Hb(cbuf,1), Cb(cbuf,1), wihT+262144, whhT+262144,
                                   nullptr, biasC, pv, cl, Hb(nbuf,1), Cb(nbuf,1), nullptr, nullptr, 512);
      int tn = (t+1 < 64) ? (t+1) : 63;
      k_lstm<<<256,256,0,stream>>>(Hb(nbuf,1), Hb(cbuf,2), Cb(cbuf,2), wihT+524288, whhT+524288,
                                   nullptr, biasC+1024, pv, cl, Hb(nbuf,2), Cb(nbuf,2),
                                   state, x + (size_t)tn*32768, 512);
    }
  }
  k_out<<<4,256,0,stream>>>(prevU, clsU, prefix, (float*)d_out);
}

// Round 4
// 10304.088 us; speedup vs baseline: 1.4606x; 1.4606x over previous
//
#include <hip/hip_runtime.h>
#include <math.h>

// T=64, B=128, H=256, C=256, K=8, L=3. One block = one sample.
// Workspace (floats): weights only — all decode state is block-private LDS.
static constexpr size_t O_EMBW  = 0;         // [256 cls][1024 (u*4+g)]  emb@Wih0^T + bih0 + bhh0
static constexpr size_t O_WPT   = 262144;    // [256 k][256 c]
static constexpr size_t O_WIHT  = 327680;    // [3][256 k][1024 (u*4+g)]
static constexpr size_t O_WHHT  = 1114112;   // [3][256 k][1024 (u*4+g)]
static constexpr size_t O_BIASC = 1900544;   // [3][256 u][4 g]  bih+bhh
// total 1903616 floats ≈ 7.6 MB

__device__ __forceinline__ float sigf(float x){ return 1.0f/(1.0f + expf(-x)); }

// ---------------- one-time prep: transposes + combined biases ----------------
__global__ __launch_bounds__(256) void k_prep(
    const float* __restrict__ Wih, const float* __restrict__ Whh,
    const float* __restrict__ Wp,  const float* __restrict__ bih,
    const float* __restrict__ bhh,
    float* __restrict__ wihT, float* __restrict__ whhT,
    float* __restrict__ WpT, float* __restrict__ biasC)
{
  const int NT = 786432;
  const int TOTAL = 2*NT + 65536 + 3072;
  int stride = gridDim.x * blockDim.x;
  for (int i = blockIdx.x*blockDim.x + threadIdx.x; i < TOTAL; i += stride){
    if (i < NT){
      int l = i / 262144, r = i % 262144;      // r = row*256 + k
      int row = r >> 8, k = r & 255;
      int g = row >> 8, u = row & 255;
      wihT[(size_t)l*262144 + (k<<10) + (u<<2) + g] = Wih[i];
    } else if (i < 2*NT){
      int j = i - NT;
      int l = j / 262144, r = j % 262144;
      int row = r >> 8, k = r & 255;
      int g = row >> 8, u = row & 255;
      whhT[(size_t)l*262144 + (k<<10) + (u<<2) + g] = Whh[j];
    } else if (i < 2*NT + 65536){
      int j = i - 2*NT; int c = j >> 8, k = j & 255;
      WpT[(k<<8) + c] = Wp[j];
    } else {
      int j = i - 2*NT - 65536;          // [3][256][4]
      int l = j >> 10; int cg = j & 1023, u = cg >> 2, g = cg & 3;
      biasC[j] = bih[l*1024 + g*256 + u] + bhh[l*1024 + g*256 + u];
    }
  }
}

// ------------- one-time: embW[cls][u*4+g] = emb@Wih0^T + bih0 + bhh0 ---------
__global__ __launch_bounds__(256) void k_embW(
    const float* __restrict__ emb, const float* __restrict__ wih0T,
    const float* __restrict__ bih, const float* __restrict__ bhh,
    float* __restrict__ embW)
{
  const int cls = blockIdx.x, u = threadIdx.x;
  const float* er = emb + cls*256;
  float a0=0.f,a1=0.f,a2=0.f,a3=0.f;
  for (int k=0;k<256;k++){
    float ev = er[k];
    float4 w = *(const float4*)&wih0T[k*1024 + u*4];
    a0 = fmaf(ev, w.x, a0); a1 = fmaf(ev, w.y, a1);
    a2 = fmaf(ev, w.z, a2); a3 = fmaf(ev, w.w, a3);
  }
  a0 += bih[u]       + bhh[u];
  a1 += bih[256+u]   + bhh[256+u];
  a2 += bih[512+u]   + bhh[512+u];
  a3 += bih[768+u]   + bhh[768+u];
  *(float4*)&embW[cls*1024 + u*4] = make_float4(a0,a1,a2,a3);
}

// ---------------- the whole decode: 1 block = 1 sample, 512 threads ----------
__global__ __launch_bounds__(512, 1) void k_decode(
    const float* __restrict__ x,      // [64][128][256]
    const float* __restrict__ WpT,    // [256 k][256 c]
    const float* __restrict__ wihT,   // [3][256 k][1024]
    const float* __restrict__ whhT,   // [3][256 k][1024]
    const float* __restrict__ biasC,  // [3][256 u][4 g]
    const float* __restrict__ embW,   // [256 cls][1024]
    const float* __restrict__ bp,     // [256]
    float* __restrict__ out)
{
  __shared__ float hS[3*2048];   // h[l][row][u]          24 KB
  __shared__ float hA[2048];     // gathered h_old rows    8 KB
  __shared__ float cS[2048];     // staged c_old[row][u]   8 KB
  __shared__ float st[2048];     // state[row][u]          8 KB
  __shared__ float jnt[2048];    // logits / joint         8 KB
  __shared__ float pfx[8];
  __shared__ float red[8];  __shared__ int redi[8];
  __shared__ float sVal[8]; __shared__ int sPrev[8], sCls[8];
  __shared__ short prevH[64*8]; __shared__ short clsH[64*8];   // 2 KB

  const int tid  = threadIdx.x;
  const int b    = blockIdx.x;
  const int u    = tid >> 1, half = tid & 1, h4 = half*4;   // LSTM map: unit, row-half
  const int wv_  = tid >> 6, lane = tid & 63;               // wave id, lane
  const int pc   = tid & 255, ph4 = (tid >> 8) * 4;         // proj map: class col, row-half

  float creg[3][4];   // c[l] for rows h4..h4+3, unit u — registers

  // ---- stage x0; init state + prefix ----
  if (tid < 64) *(float4*)&hA[tid*4] = *(const float4*)&x[(size_t)b*256 + tid*4];
  if (tid < 8)  pfx[tid] = (tid==0) ? 0.0f : -1e30f;
  __syncthreads();
  *(float4*)&st[tid*4] = *(const float4*)&hA[(tid&63)*4];   // broadcast x0 to 8 rows

  // ---- init LSTM from zero state: gates = x0 @ wihT_l + (bih+bhh), M=1 ----
  for (int l=0; l<3; l++){
    if (half == 0){
      const float* Wg = wihT + (size_t)l*262144;
      float acc0=0.f, acc1=0.f, acc2=0.f, acc3=0.f;
      for (int kc=0; kc<256; kc+=4){
        float4 a4 = *(const float4*)&hA[kc];
        float4 w0 = *(const float4*)&Wg[(size_t)(kc+0)*1024 + u*4];
        float4 w1 = *(const float4*)&Wg[(size_t)(kc+1)*1024 + u*4];
        float4 w2 = *(const float4*)&Wg[(size_t)(kc+2)*1024 + u*4];
        float4 w3 = *(const float4*)&Wg[(size_t)(kc+3)*1024 + u*4];
        acc0=fmaf(a4.x,w0.x,acc0); acc0=fmaf(a4.y,w1.x,acc0); acc0=fmaf(a4.z,w2.x,acc0); acc0=fmaf(a4.w,w3.x,acc0);
        acc1=fmaf(a4.x,w0.y,acc1); acc1=fmaf(a4.y,w1.y,acc1); acc1=fmaf(a4.z,w2.y,acc1); acc1=fmaf(a4.w,w3.y,acc1);
        acc2=fmaf(a4.x,w0.z,acc2); acc2=fmaf(a4.y,w1.z,acc2); acc2=fmaf(a4.z,w2.z,acc2); acc2=fmaf(a4.w,w3.z,acc2);
        acc3=fmaf(a4.x,w0.w,acc3); acc3=fmaf(a4.y,w1.w,acc3); acc3=fmaf(a4.z,w2.w,acc3); acc3=fmaf(a4.w,w3.w,acc3);
      }
      float4 bs = *(const float4*)&biasC[(l*256+u)*4];
      float gi = acc0+bs.x, gg = acc2+bs.z, go = acc3+bs.w;  // c_old=0: forget term vanishes
      float cn = sigf(gi)*tanhf(gg);
      float hn = sigf(go)*tanhf(cn);
      jnt[u] = hn; jnt[1024+u] = cn;
    }
    __syncthreads();
    *(float4*)&hS[l*2048 + tid*4] = *(const float4*)&jnt[(tid&63)*4];  // broadcast h to 8 rows
    {
      float cv = jnt[1024+u];
      #pragma unroll
      for (int i=0;i<4;i++) creg[l][i] = cv;
    }
    __syncthreads();
    if (tid < 64) *(float4*)&hA[tid*4] = *(const float4*)&jnt[tid*4];  // next layer's input row
    __syncthreads();
  }

  // GEMM for 4 rows (h4..h4+3) x 4 gate-cols (u*4..u*4+3), K=256, A in LDS, W in global
  auto gemm_part = [&](const float* A, const float* Wg, float* acc){
    const float* Ar = A + h4*256;
    const float* Wr = Wg + u*4;
    float4 wn0 = *(const float4*)&Wr[0];
    float4 wn1 = *(const float4*)&Wr[1024];
    float4 wn2 = *(const float4*)&Wr[2048];
    float4 wn3 = *(const float4*)&Wr[3072];
    float4 an0 = *(const float4*)&Ar[0];
    float4 an1 = *(const float4*)&Ar[256];
    float4 an2 = *(const float4*)&Ar[512];
    float4 an3 = *(const float4*)&Ar[768];
    #pragma unroll 1
    for (int kc=0; kc<256; kc+=4){
      float4 w0=wn0, w1=wn1, w2=wn2, w3=wn3;
      float4 a0=an0, a1=an1, a2=an2, a3=an3;
      if (kc+4 < 256){
        const float* Wn = Wr + (size_t)(kc+4)*1024;
        wn0 = *(const float4*)&Wn[0];
        wn1 = *(const float4*)&Wn[1024];
        wn2 = *(const float4*)&Wn[2048];
        wn3 = *(const float4*)&Wn[3072];
        an0 = *(const float4*)&Ar[kc+4];
        an1 = *(const float4*)&Ar[256+kc+4];
        an2 = *(const float4*)&Ar[512+kc+4];
        an3 = *(const float4*)&Ar[768+kc+4];
      }
      float W4[4][4] = {{w0.x,w0.y,w0.z,w0.w},{w1.x,w1.y,w1.z,w1.w},
                        {w2.x,w2.y,w2.z,w2.w},{w3.x,w3.y,w3.z,w3.w}};
      float A4[4][4] = {{a0.x,a0.y,a0.z,a0.w},{a1.x,a1.y,a1.z,a1.w},
                        {a2.x,a2.y,a2.z,a2.w},{a3.x,a3.y,a3.z,a3.w}};
      #pragma unroll
      for (int i=0;i<4;i++)
        #pragma unroll
        for (int kk=0;kk<4;kk++)
          #pragma unroll
          for (int j=0;j<4;j++)
            acc[i*4+j] = fmaf(A4[i][kk], W4[kk][j], acc[i*4+j]);
    }
  };

  // ---------------- 64 decode steps, all block-local ----------------
  for (int t=0; t<64; t++){
    __syncthreads();   // st stable

    // ---- proj GEMM: logits[row][c] = st[row] @ WpT + bp ----
    {
      const float* A = st + ph4*256;
      float p0=0.f,p1=0.f,p2=0.f,p3=0.f;
      for (int kc=0; kc<256; kc+=4){
        float4 a0 = *(const float4*)&A[kc];
        float4 a1 = *(const float4*)&A[256+kc];
        float4 a2 = *(const float4*)&A[512+kc];
        float4 a3 = *(const float4*)&A[768+kc];
        float w0 = WpT[(kc+0)*256+pc], w1 = WpT[(kc+1)*256+pc],
              w2 = WpT[(kc+2)*256+pc], w3 = WpT[(kc+3)*256+pc];
        p0=fmaf(a0.x,w0,p0); p0=fmaf(a0.y,w1,p0); p0=fmaf(a0.z,w2,p0); p0=fmaf(a0.w,w3,p0);
        p1=fmaf(a1.x,w0,p1); p1=fmaf(a1.y,w1,p1); p1=fmaf(a1.z,w2,p1); p1=fmaf(a1.w,w3,p1);
        p2=fmaf(a2.x,w0,p2); p2=fmaf(a2.y,w1,p2); p2=fmaf(a2.z,w2,p2); p2=fmaf(a2.w,w3,p2);
        p3=fmaf(a3.x,w0,p3); p3=fmaf(a3.y,w1,p3); p3=fmaf(a3.z,w2,p3); p3=fmaf(a3.w,w3,p3);
      }
      float bpc = bp[pc];
      jnt[(ph4+0)*256+pc] = p0+bpc;
      jnt[(ph4+1)*256+pc] = p1+bpc;
      jnt[(ph4+2)*256+pc] = p2+bpc;
      jnt[(ph4+3)*256+pc] = p3+bpc;
    }
    __syncthreads();

    // ---- log-softmax + prefix: wave w handles beam-row w ----
    {
      const int kb = wv_;
      float4 v = *(const float4*)&jnt[kb*256 + lane*4];
      float m = fmaxf(fmaxf(v.x,v.y),fmaxf(v.z,v.w));
      for (int off=32;off;off>>=1) m = fmaxf(m, __shfl_down(m,off));
      m = __shfl(m, 0);
      double s = exp((double)v.x-(double)m)+exp((double)v.y-(double)m)
               + exp((double)v.z-(double)m)+exp((double)v.w-(double)m);
      for (int off=32;off;off>>=1) s += __shfl_down(s,off);
      s = __shfl(s, 0);
      double lse = log(s);
      float pf = pfx[kb];
      float4 o;
      o.x = (float)((double)v.x - (double)m - lse) + pf;
      o.y = (float)((double)v.y - (double)m - lse) + pf;
      o.z = (float)((double)v.z - (double)m - lse) + pf;
      o.w = (float)((double)v.w - (double)m - lse) + pf;
      *(float4*)&jnt[kb*256+lane*4] = o;
    }
    __syncthreads();

    // ---- top-8 of joint[2048]: ascending-scan strict-> keeps lowest idx ----
    for (int r=0;r<8;r++){
      float bv = -INFINITY; int bi = 0;
      #pragma unroll
      for (int i=0;i<4;i++){
        int idx = tid*4+i; float vv = jnt[idx];
        if (vv > bv){ bv=vv; bi=idx; }
      }
      for (int off=32;off;off>>=1){
        float ov = __shfl_down(bv,off); int oi = __shfl_down(bi,off);
        if (ov>bv || (ov==bv && oi<bi)){ bv=ov; bi=oi; }
      }
      if (lane==0){ red[wv_]=bv; redi[wv_]=bi; }
      __syncthreads();
      if (tid==0){
        float BV=red[0]; int BI=redi[0];
        for (int j=1;j<8;j++) if (red[j]>BV || (red[j]==BV && redi[j]<BI)){BV=red[j];BI=redi[j];}
        sVal[r]=BV; sPrev[r]=BI>>8; sCls[r]=BI&255;
        jnt[BI] = -INFINITY;
      }
      __syncthreads();
    }
    if (tid<8){
      pfx[tid] = sVal[tid];
      prevH[t*8+tid] = (short)sPrev[tid];
      clsH[t*8+tid]  = (short)sCls[tid];
    }
    __syncthreads();

    // ---- 3 LSTM layers ----
    for (int l=0; l<3; l++){
      // gather h_old rows into hA; stage c_old into cS
      {
        int r = tid>>6, k0 = (tid&63)*4;
        int gr = sPrev[r];
        *(float4*)&hA[r*256+k0] = *(const float4*)&hS[l*2048 + gr*256 + k0];
        #pragma unroll
        for (int i=0;i<4;i++) cS[(h4+i)*256 + u] = creg[l][i];
      }
      __syncthreads();

      float acc[16];
      #pragma unroll
      for (int i=0;i<16;i++) acc[i]=0.f;
      if (l > 0) gemm_part(hS + (l-1)*2048, wihT + (size_t)l*262144, acc);  // dense input
      gemm_part(hA, whhT + (size_t)l*262144, acc);                          // recurrent (gathered)

      // epilogue: LSTM cell for 4 (row, unit) cells
      {
        const int tn = (t < 63) ? (t+1) : 63;
        float xv = 0.f;
        if (l == 2) xv = x[(size_t)tn*32768 + b*256 + u];
        #pragma unroll
        for (int i=0;i<4;i++){
          int R = h4 + i;
          float4 base = (l==0)
              ? *(const float4*)&embW[(size_t)sCls[R]*1024 + u*4]
              : *(const float4*)&biasC[(l*256+u)*4];
          float co = cS[sPrev[R]*256 + u];
          float gi = acc[i*4+0] + base.x;
          float gf = acc[i*4+1] + base.y;
          float gg = acc[i*4+2] + base.z;
          float go = acc[i*4+3] + base.w;
          float cn = sigf(gf)*co + sigf(gi)*tanhf(gg);
          float hn = sigf(go)*tanhf(cn);
          creg[l][i] = cn;
          hS[l*2048 + R*256 + u] = hn;
          if (l == 2) st[R*256 + u] = hn + xv;
        }
      }
      __syncthreads();
    }
  }

  // ---- backtrace choices + prefix ----
  if (tid < 8){
    int e = tid;
    for (int tt=63; tt>=0; --tt){
      out[(size_t)(b*8+tid)*64 + tt] = (float)clsH[tt*8+e];
      e = (int)prevH[tt*8+e];
    }
    out[65536 + b*8 + tid] = pfx[tid];
  }
}

extern "C" void kernel_launch(void* const* d_in, const int* in_sizes, int n_in,
                              void* d_out, int out_size, void* d_ws, size_t ws_size,
                              hipStream_t stream)
{
  const float* x   = (const float*)d_in[0];
  const float* emb = (const float*)d_in[1];
  const float* Wih = (const float*)d_in[2];
  const float* Whh = (const float*)d_in[3];
  const float* bih = (const float*)d_in[4];
  const float* bhh = (const float*)d_in[5];
  const float* Wp  = (const float*)d_in[6];
  const float* bp  = (const float*)d_in[7];
  float* ws = (float*)d_ws;

  float* embW  = ws + O_EMBW;
  float* WpT   = ws + O_WPT;
  float* wihT  = ws + O_WIHT;
  float* whhT  = ws + O_WHHT;
  float* biasC = ws + O_BIASC;

  k_prep<<<256,256,0,stream>>>(Wih,Whh,Wp,bih,bhh,wihT,whhT,WpT,biasC);
  k_embW<<<256,256,0,stream>>>(emb, wihT, bih, bhh, embW);
  k_decode<<<128,512,0,stream>>>(x, WpT, wihT, whhT, biasC, embW, bp, (float*)d_out);
}

// Round 5
// 7536.689 us; speedup vs baseline: 1.9970x; 1.3672x over previous
//
#include <hip/hip_runtime.h>
#include <math.h>

// T=64, B=128, H=256, C=256, K=8, L=3. One block = one sample.
// Workspace (floats): weights only — all decode state is block-private LDS.
static constexpr size_t O_EMBW  = 0;         // [256 cls][1024 (u*4+g)]  emb@Wih0^T + bih0 + bhh0
static constexpr size_t O_WPT   = 262144;    // [256 k][256 c]
static constexpr size_t O_WIHT  = 327680;    // [3][256 k][1024 (u*4+g)]
static constexpr size_t O_WHHT  = 1114112;   // [3][256 k][1024 (u*4+g)]
static constexpr size_t O_BIASC = 1900544;   // [3][256 u][4 g]  bih+bhh
// total 1903616 floats ≈ 7.6 MB

__device__ __forceinline__ float sigf(float x){ return 1.0f/(1.0f + expf(-x)); }

// ---------------- one-time prep: transposes + combined biases ----------------
__global__ __launch_bounds__(256) void k_prep(
    const float* __restrict__ Wih, const float* __restrict__ Whh,
    const float* __restrict__ Wp,  const float* __restrict__ bih,
    const float* __restrict__ bhh,
    float* __restrict__ wihT, float* __restrict__ whhT,
    float* __restrict__ WpT, float* __restrict__ biasC)
{
  const int NT = 786432;
  const int TOTAL = 2*NT + 65536 + 3072;
  int stride = gridDim.x * blockDim.x;
  for (int i = blockIdx.x*blockDim.x + threadIdx.x; i < TOTAL; i += stride){
    if (i < NT){
      int l = i / 262144, r = i % 262144;      // r = row*256 + k
      int row = r >> 8, k = r & 255;
      int g = row >> 8, u = row & 255;
      wihT[(size_t)l*262144 + (k<<10) + (u<<2) + g] = Wih[i];
    } else if (i < 2*NT){
      int j = i - NT;
      int l = j / 262144, r = j % 262144;
      int row = r >> 8, k = r & 255;
      int g = row >> 8, u = row & 255;
      whhT[(size_t)l*262144 + (k<<10) + (u<<2) + g] = Whh[j];
    } else if (i < 2*NT + 65536){
      int j = i - 2*NT; int c = j >> 8, k = j & 255;
      WpT[(k<<8) + c] = Wp[j];
    } else {
      int j = i - 2*NT - 65536;          // [3][256][4]
      int l = j >> 10; int cg = j & 1023, u = cg >> 2, g = cg & 3;
      biasC[j] = bih[l*1024 + g*256 + u] + bhh[l*1024 + g*256 + u];
    }
  }
}

// ------------- one-time: embW[cls][u*4+g] = emb@Wih0^T + bih0 + bhh0 ---------
__global__ __launch_bounds__(256) void k_embW(
    const float* __restrict__ emb, const float* __restrict__ wih0T,
    const float* __restrict__ bih, const float* __restrict__ bhh,
    float* __restrict__ embW)
{
  const int cls = blockIdx.x, u = threadIdx.x;
  const float* er = emb + cls*256;
  float a0=0.f,a1=0.f,a2=0.f,a3=0.f;
  for (int k=0;k<256;k++){
    float ev = er[k];
    float4 w = *(const float4*)&wih0T[k*1024 + u*4];
    a0 = fmaf(ev, w.x, a0); a1 = fmaf(ev, w.y, a1);
    a2 = fmaf(ev, w.z, a2); a3 = fmaf(ev, w.w, a3);
  }
  a0 += bih[u]       + bhh[u];
  a1 += bih[256+u]   + bhh[256+u];
  a2 += bih[512+u]   + bhh[512+u];
  a3 += bih[768+u]   + bhh[768+u];
  *(float4*)&embW[cls*1024 + u*4] = make_float4(a0,a1,a2,a3);
}

// ---------------- the whole decode: 1 block = 1 sample, 512 threads ----------
__global__ __launch_bounds__(512, 2) void k_decode(
    const float* __restrict__ x,      // [64][128][256]
    const float* __restrict__ WpT,    // [256 k][256 c]
    const float* __restrict__ wihT,   // [3][256 k][1024]
    const float* __restrict__ whhT,   // [3][256 k][1024]
    const float* __restrict__ biasC,  // [3][256 u][4 g]
    const float* __restrict__ embW,   // [256 cls][1024]
    const float* __restrict__ bp,     // [256]
    float* __restrict__ out)
{
  __shared__ float hS[3*2048];   // h[l][row][u]          24 KB
  __shared__ float cS[2048];     // staged c_old[row][u]   8 KB
  __shared__ float st[2048];     // state[row][u]          8 KB
  __shared__ float jnt[2048];    // logits / joint         8 KB
  __shared__ float pfx[8];
  __shared__ float red[8];  __shared__ int redi[8];
  __shared__ float sVal[8]; __shared__ int sPrev[8], sCls[8];
  __shared__ short prevH[64*8]; __shared__ short clsH[64*8];   // 2 KB

  const int tid  = threadIdx.x;
  const int b    = blockIdx.x;
  const int u    = tid >> 1, half = tid & 1, h4 = half*4;   // LSTM map: unit, row-half
  const int wv_  = tid >> 6, lane = tid & 63;               // wave id, lane
  const int pc   = tid & 255, ph4 = (tid >> 8) * 4;         // proj map: class col, row-half

  float creg[3][4];   // c[l] for rows h4..h4+3, unit u — registers

  // ---- stage x0; init state + prefix ----
  if (tid < 64) *(float4*)&jnt[tid*4] = *(const float4*)&x[(size_t)b*256 + tid*4];
  if (tid < 8)  pfx[tid] = (tid==0) ? 0.0f : -1e30f;
  __syncthreads();
  *(float4*)&st[tid*4] = *(const float4*)&jnt[(tid&63)*4];   // broadcast x0 to 8 rows
  __syncthreads();
  if (tid < 64) *(float4*)&cS[tid*4] = *(const float4*)&jnt[tid*4];  // layer input row (reuse cS)
  __syncthreads();

  // ---- init LSTM from zero state: gates = in @ wihT_l + (bih+bhh), M=1 ----
  for (int l=0; l<3; l++){
    if (half == 0){
      const float* Wg = wihT + (size_t)l*262144;
      float acc0=0.f, acc1=0.f, acc2=0.f, acc3=0.f;
      for (int kc=0; kc<256; kc+=4){
        float4 a4 = *(const float4*)&cS[kc];
        float4 w0 = *(const float4*)&Wg[(size_t)(kc+0)*1024 + u*4];
        float4 w1 = *(const float4*)&Wg[(size_t)(kc+1)*1024 + u*4];
        float4 w2 = *(const float4*)&Wg[(size_t)(kc+2)*1024 + u*4];
        float4 w3 = *(const float4*)&Wg[(size_t)(kc+3)*1024 + u*4];
        acc0=fmaf(a4.x,w0.x,acc0); acc0=fmaf(a4.y,w1.x,acc0); acc0=fmaf(a4.z,w2.x,acc0); acc0=fmaf(a4.w,w3.x,acc0);
        acc1=fmaf(a4.x,w0.y,acc1); acc1=fmaf(a4.y,w1.y,acc1); acc1=fmaf(a4.z,w2.y,acc1); acc1=fmaf(a4.w,w3.y,acc1);
        acc2=fmaf(a4.x,w0.z,acc2); acc2=fmaf(a4.y,w1.z,acc2); acc2=fmaf(a4.z,w2.z,acc2); acc2=fmaf(a4.w,w3.z,acc2);
        acc3=fmaf(a4.x,w0.w,acc3); acc3=fmaf(a4.y,w1.w,acc3); acc3=fmaf(a4.z,w2.w,acc3); acc3=fmaf(a4.w,w3.w,acc3);
      }
      float4 bs = *(const float4*)&biasC[(l*256+u)*4];
      float gi = acc0+bs.x, gg = acc2+bs.z, go = acc3+bs.w;  // c_old=0: forget term vanishes
      float cn = sigf(gi)*tanhf(gg);
      float hn = sigf(go)*tanhf(cn);
      jnt[u] = hn; jnt[1024+u] = cn;
    }
    __syncthreads();
    *(float4*)&hS[l*2048 + tid*4] = *(const float4*)&jnt[(tid&63)*4];  // broadcast h to 8 rows
    {
      float cv = jnt[1024+u];
      #pragma unroll
      for (int i=0;i<4;i++) creg[l][i] = cv;
    }
    __syncthreads();
    if (tid < 64) *(float4*)&cS[tid*4] = *(const float4*)&jnt[tid*4];  // next layer's input row
    __syncthreads();
  }

  // GEMM for 4 rows x 4 gate-cols (u*4..u*4+3), K=256.
  // A rows from LDS (ro* = float offsets into hbase); W from global with
  // 4-stage rolling register prefetch (12 float4 in flight -> covers L3 latency).
  auto gemm_part = [&](const float* hbase, int ro0, int ro1, int ro2, int ro3,
                       const float* Wg, float* acc){
    const float* Wr = Wg + u*4;
    float4 wst[4][4];
    #pragma unroll
    for (int s=0; s<4; s++){
      const float* Wn = Wr + (size_t)(s*4)*1024;
      wst[s][0] = *(const float4*)&Wn[0];
      wst[s][1] = *(const float4*)&Wn[1024];
      wst[s][2] = *(const float4*)&Wn[2048];
      wst[s][3] = *(const float4*)&Wn[3072];
    }
    #pragma unroll 1
    for (int kc=0; kc<240; kc+=16){
      #pragma unroll
      for (int sub=0; sub<4; sub++){
        const int kcur = kc + sub*4;
        float4 w0 = wst[sub][0], w1 = wst[sub][1], w2 = wst[sub][2], w3 = wst[sub][3];
        const float* Wn = Wr + (size_t)(kcur+16)*1024;   // refill: consumed 4 iters later
        wst[sub][0] = *(const float4*)&Wn[0];
        wst[sub][1] = *(const float4*)&Wn[1024];
        wst[sub][2] = *(const float4*)&Wn[2048];
        wst[sub][3] = *(const float4*)&Wn[3072];
        float4 a0 = *(const float4*)&hbase[ro0 + kcur];
        float4 a1 = *(const float4*)&hbase[ro1 + kcur];
        float4 a2 = *(const float4*)&hbase[ro2 + kcur];
        float4 a3 = *(const float4*)&hbase[ro3 + kcur];
        float W4[4][4] = {{w0.x,w0.y,w0.z,w0.w},{w1.x,w1.y,w1.z,w1.w},
                          {w2.x,w2.y,w2.z,w2.w},{w3.x,w3.y,w3.z,w3.w}};
        float A4[4][4] = {{a0.x,a0.y,a0.z,a0.w},{a1.x,a1.y,a1.z,a1.w},
                          {a2.x,a2.y,a2.z,a2.w},{a3.x,a3.y,a3.z,a3.w}};
        #pragma unroll
        for (int i=0;i<4;i++)
          #pragma unroll
          for (int kk=0;kk<4;kk++)
            #pragma unroll
            for (int j=0;j<4;j++)
              acc[i*4+j] = fmaf(A4[i][kk], W4[kk][j], acc[i*4+j]);
      }
    }
    {  // tail kc=240..252: consume remaining stages, no refill
      const int kc = 240;
      #pragma unroll
      for (int sub=0; sub<4; sub++){
        const int kcur = kc + sub*4;
        float4 w0 = wst[sub][0], w1 = wst[sub][1], w2 = wst[sub][2], w3 = wst[sub][3];
        float4 a0 = *(const float4*)&hbase[ro0 + kcur];
        float4 a1 = *(const float4*)&hbase[ro1 + kcur];
        float4 a2 = *(const float4*)&hbase[ro2 + kcur];
        float4 a3 = *(const float4*)&hbase[ro3 + kcur];
        float W4[4][4] = {{w0.x,w0.y,w0.z,w0.w},{w1.x,w1.y,w1.z,w1.w},
                          {w2.x,w2.y,w2.z,w2.w},{w3.x,w3.y,w3.z,w3.w}};
        float A4[4][4] = {{a0.x,a0.y,a0.z,a0.w},{a1.x,a1.y,a1.z,a1.w},
                          {a2.x,a2.y,a2.z,a2.w},{a3.x,a3.y,a3.z,a3.w}};
        #pragma unroll
        for (int i=0;i<4;i++)
          #pragma unroll
          for (int kk=0;kk<4;kk++)
            #pragma unroll
            for (int j=0;j<4;j++)
              acc[i*4+j] = fmaf(A4[i][kk], W4[kk][j], acc[i*4+j]);
      }
    }
  };

  // ---------------- 64 decode steps, all block-local ----------------
  for (int t=0; t<64; t++){
    __syncthreads();   // st stable

    // ---- proj GEMM: logits[row][c] = st[row] @ WpT + bp (4-stage prefetch) ----
    {
      const float* A = st + ph4*256;
      const float* Wc = WpT + pc;
      float p0=0.f,p1=0.f,p2=0.f,p3=0.f;
      float wst[4][4];
      #pragma unroll
      for (int s=0;s<4;s++){
        #pragma unroll
        for (int q=0;q<4;q++) wst[s][q] = Wc[(s*4+q)*256];
      }
      #pragma unroll 1
      for (int kc=0; kc<240; kc+=16){
        #pragma unroll
        for (int sub=0; sub<4; sub++){
          const int kcur = kc + sub*4;
          float w0=wst[sub][0], w1=wst[sub][1], w2=wst[sub][2], w3=wst[sub][3];
          #pragma unroll
          for (int q=0;q<4;q++) wst[sub][q] = Wc[(kcur+16+q)*256];
          float4 a0 = *(const float4*)&A[kcur];
          float4 a1 = *(const float4*)&A[256+kcur];
          float4 a2 = *(const float4*)&A[512+kcur];
          float4 a3 = *(const float4*)&A[768+kcur];
          p0=fmaf(a0.x,w0,p0); p0=fmaf(a0.y,w1,p0); p0=fmaf(a0.z,w2,p0); p0=fmaf(a0.w,w3,p0);
          p1=fmaf(a1.x,w0,p1); p1=fmaf(a1.y,w1,p1); p1=fmaf(a1.z,w2,p1); p1=fmaf(a1.w,w3,p1);
          p2=fmaf(a2.x,w0,p2); p2=fmaf(a2.y,w1,p2); p2=fmaf(a2.z,w2,p2); p2=fmaf(a2.w,w3,p2);
          p3=fmaf(a3.x,w0,p3); p3=fmaf(a3.y,w1,p3); p3=fmaf(a3.z,w2,p3); p3=fmaf(a3.w,w3,p3);
        }
      }
      {
        const int kc = 240;
        #pragma unroll
        for (int sub=0; sub<4; sub++){
          const int kcur = kc + sub*4;
          float w0=wst[sub][0], w1=wst[sub][1], w2=wst[sub][2], w3=wst[sub][3];
          float4 a0 = *(const float4*)&A[kcur];
          float4 a1 = *(const float4*)&A[256+kcur];
          float4 a2 = *(const float4*)&A[512+kcur];
          float4 a3 = *(const float4*)&A[768+kcur];
          p0=fmaf(a0.x,w0,p0); p0=fmaf(a0.y,w1,p0); p0=fmaf(a0.z,w2,p0); p0=fmaf(a0.w,w3,p0);
          p1=fmaf(a1.x,w0,p1); p1=fmaf(a1.y,w1,p1); p1=fmaf(a1.z,w2,p1); p1=fmaf(a1.w,w3,p1);
          p2=fmaf(a2.x,w0,p2); p2=fmaf(a2.y,w1,p2); p2=fmaf(a2.z,w2,p2); p2=fmaf(a2.w,w3,p2);
          p3=fmaf(a3.x,w0,p3); p3=fmaf(a3.y,w1,p3); p3=fmaf(a3.z,w2,p3); p3=fmaf(a3.w,w3,p3);
        }
      }
      float bpc = bp[pc];
      jnt[(ph4+0)*256+pc] = p0+bpc;
      jnt[(ph4+1)*256+pc] = p1+bpc;
      jnt[(ph4+2)*256+pc] = p2+bpc;
      jnt[(ph4+3)*256+pc] = p3+bpc;
    }
    __syncthreads();

    // ---- log-softmax + prefix: wave w handles beam-row w ----
    {
      const int kb = wv_;
      float4 v = *(const float4*)&jnt[kb*256 + lane*4];
      float m = fmaxf(fmaxf(v.x,v.y),fmaxf(v.z,v.w));
      for (int off=32;off;off>>=1) m = fmaxf(m, __shfl_down(m,off));
      m = __shfl(m, 0);
      double s = exp((double)v.x-(double)m)+exp((double)v.y-(double)m)
               + exp((double)v.z-(double)m)+exp((double)v.w-(double)m);
      for (int off=32;off;off>>=1) s += __shfl_down(s,off);
      s = __shfl(s, 0);
      double lse = log(s);
      float pf = pfx[kb];
      float4 o;
      o.x = (float)((double)v.x - (double)m - lse) + pf;
      o.y = (float)((double)v.y - (double)m - lse) + pf;
      o.z = (float)((double)v.z - (double)m - lse) + pf;
      o.w = (float)((double)v.w - (double)m - lse) + pf;
      *(float4*)&jnt[kb*256+lane*4] = o;
    }
    __syncthreads();

    // ---- top-8 of joint[2048]; stride-512 scan (conflict-free), (val, lowest-idx) ----
    for (int r=0;r<8;r++){
      float bv = -INFINITY; int bi = 0;
      #pragma unroll
      for (int i=0;i<4;i++){
        int idx = tid + 512*i; float vv = jnt[idx];
        if (vv > bv){ bv=vv; bi=idx; }     // i ascending => idx ascending
      }
      for (int off=32;off;off>>=1){
        float ov = __shfl_down(bv,off); int oi = __shfl_down(bi,off);
        if (ov>bv || (ov==bv && oi<bi)){ bv=ov; bi=oi; }
      }
      if (lane==0){ red[wv_]=bv; redi[wv_]=bi; }
      __syncthreads();
      if (tid==0){
        float BV=red[0]; int BI=redi[0];
        for (int j=1;j<8;j++) if (red[j]>BV || (red[j]==BV && redi[j]<BI)){BV=red[j];BI=redi[j];}
        sVal[r]=BV; sPrev[r]=BI>>8; sCls[r]=BI&255;
        jnt[BI] = -INFINITY;
      }
      __syncthreads();
    }
    if (tid<8){
      pfx[tid] = sVal[tid];
      prevH[t*8+tid] = (short)sPrev[tid];
      clsH[t*8+tid]  = (short)sCls[tid];
    }
    __syncthreads();

    // per-step beam bookkeeping (read once; sPrev/sCls stable until next step)
    int pvr[4], clr[4], rog[4];
    #pragma unroll
    for (int i=0;i<4;i++){
      pvr[i] = sPrev[h4+i];
      clr[i] = sCls[h4+i];
      rog[i] = pvr[i]*256;
    }

    // ---- 3 LSTM layers ----
    #pragma unroll 1
    for (int l=0; l<3; l++){
      // stage c_old for the gather
      #pragma unroll
      for (int i=0;i<4;i++) cS[(h4+i)*256 + u] = creg[l][i];
      __syncthreads();   // cS visible; hS stable

      float acc[16];
      #pragma unroll
      for (int i=0;i<16;i++) acc[i]=0.f;
      if (l > 0){  // dense input stream: rows h4..h4+3 of hS[l-1]
        gemm_part(hS + (l-1)*2048, (h4+0)*256, (h4+1)*256, (h4+2)*256, (h4+3)*256,
                  wihT + (size_t)l*262144, acc);
      }
      // recurrent stream: gathered rows of hS[l]
      gemm_part(hS + l*2048, rog[0], rog[1], rog[2], rog[3],
                whhT + (size_t)l*262144, acc);
      __syncthreads();   // all reads of hS[l] (old) and cS done

      // epilogue: LSTM cell for 4 (row, unit) cells
      {
        const int tn = (t < 63) ? (t+1) : 63;
        float xv = 0.f;
        if (l == 2) xv = x[(size_t)tn*32768 + b*256 + u];
        #pragma unroll
        for (int i=0;i<4;i++){
          int R = h4 + i;
          float4 base = (l==0)
              ? *(const float4*)&embW[(size_t)clr[i]*1024 + u*4]
              : *(const float4*)&biasC[(l*256+u)*4];
          float co = cS[rog[i] + u];
          float gi = acc[i*4+0] + base.x;
          float gf = acc[i*4+1] + base.y;
          float gg = acc[i*4+2] + base.z;
          float go = acc[i*4+3] + base.w;
          float cn = sigf(gf)*co + sigf(gi)*tanhf(gg);
          float hn = sigf(go)*tanhf(cn);
          creg[l][i] = cn;
          hS[l*2048 + R*256 + u] = hn;
          if (l == 2) st[R*256 + u] = hn + xv;
        }
      }
      __syncthreads();   // epilogue writes visible (next layer / next step)
    }
  }

  // ---- backtrace choices + prefix ----
  if (tid < 8){
    int e = tid;
    for (int tt=63; tt>=0; --tt){
      out[(size_t)(b*8+tid)*64 + tt] = (float)clsH[tt*8+e];
      e = (int)prevH[tt*8+e];
    }
    out[65536 + b*8 + tid] = pfx[tid];
  }
}

extern "C" void kernel_launch(void* const* d_in, const int* in_sizes, int n_in,
                              void* d_out, int out_size, void* d_ws, size_t ws_size,
                              hipStream_t stream)
{
  const float* x   = (const float*)d_in[0];
  const float* emb = (const float*)d_in[1];
  const float* Wih = (const float*)d_in[2];
  const float* Whh = (const float*)d_in[3];
  const float* bih = (const float*)d_in[4];
  const float* bhh = (const float*)d_in[5];
  const float* Wp  = (const float*)d_in[6];
  const float* bp  = (const float*)d_in[7];
  float* ws = (float*)d_ws;

  float* embW  = ws + O_EMBW;
  float* WpT   = ws + O_WPT;
  float* wihT  = ws + O_WIHT;
  float* whhT  = ws + O_WHHT;
  float* biasC = ws + O_BIASC;

  k_prep<<<256,256,0,stream>>>(Wih,Whh,Wp,bih,bhh,wihT,whhT,WpT,biasC);
  k_embW<<<256,256,0,stream>>>(emb, wihT, bih, bhh, embW);
  k_decode<<<128,512,0,stream>>>(x, WpT, wihT, whhT, biasC, embW, bp, (float*)d_out);
}